// Round 21
// baseline (190.914 us; speedup 1.0000x reference)
//
#include <hip/hip_runtime.h>

#define B_ 8
#define L_ 2048
#define N_ 512
#define H_ 16
#define C_ 16
#define D_ 64
#define TK_ 45
#define KS_ 16

typedef __attribute__((ext_vector_type(8))) short bf16x8;
typedef __attribute__((ext_vector_type(4))) float f32x4;

__device__ __forceinline__ float sigmoidf_(float v) { return 1.f / (1.f + expf(-v)); }

__device__ __forceinline__ short f2bf(float f) {
  union { float f; unsigned u; } v; v.f = f;
  unsigned r = (v.u + 0x7fffu + ((v.u >> 16) & 1u)) >> 16;
  return (short)r;
}
__device__ __forceinline__ float bf2f(short s) {
  union { unsigned u; float f; } v; v.u = ((unsigned)(unsigned short)s) << 16;
  return v.f;
}
__device__ __forceinline__ void gload16(const void* g, void* l) {
  __builtin_amdgcn_global_load_lds((const __attribute__((address_space(1))) unsigned int*)g,
                                   (__attribute__((address_space(3))) unsigned int*)l, 16, 0, 0);
}

// ---------------- 1. single-pass x (0-511) + VE (512-543) + ABC (544)
//                   + vei (545-546) + cwmisc (547) ----------------
__global__ __launch_bounds__(512) void k_pre(const float* __restrict__ x,
                                             const float* __restrict__ var_embed,
                                             const float* __restrict__ temp_w,
                                             const float* __restrict__ temp_b,
                                             const float* __restrict__ q_w,
                                             const float* __restrict__ q_b,
                                             const float* __restrict__ k_w,
                                             const float* __restrict__ k_b,
                                             const float* __restrict__ imp_w,
                                             const float* __restrict__ imp_b,
                                             const float* __restrict__ cs,
                                             const float* __restrict__ cp2_w,
                                             const float* __restrict__ cp2_b,
                                             const float* __restrict__ vp_b,
                                             const float* __restrict__ vp_w,
                                             const float* __restrict__ cp1_w,
                                             float* __restrict__ normed,
                                             float* __restrict__ psum,
                                             float* __restrict__ psq,
                                             short* __restrict__ xbf,
                                             float* __restrict__ veq,
                                             float* __restrict__ vek,
                                             float* __restrict__ abc,
                                             float* __restrict__ vei,
                                             float* __restrict__ cw,
                                             float* __restrict__ misc) {
  int blk = blockIdx.x, t = threadIdx.x;
  if (blk < 512) {
    int l0 = blk * 4;
    int n = t;
    float row_s[4] = {}, row_ss[4] = {};
#pragma unroll
    for (int b = 0; b < B_; ++b) {
      float bs = 0.f, bss = 0.f;
#pragma unroll
      for (int r = 0; r < 4; ++r) {
        float v = x[((size_t)b * L_ + l0 + r) * N_ + n];
        bs += v; bss += v * v;
        row_s[r] += v; row_ss[r] += v * v;
        xbf[((size_t)b * L_ + l0 + r) * N_ + n] = f2bf(v);
      }
      psum[((size_t)b * 512 + blk) * N_ + n] = bs;
      psq [((size_t)b * 512 + blk) * N_ + n] = bss;
    }
#pragma unroll
    for (int r = 0; r < 4; ++r) {
      float mean = row_s[r] * (1.f / B_);
      float var  = fmaxf((row_ss[r] - row_s[r] * mean) * (1.f / (B_ - 1)), 0.f);
      normed[(l0 + r) * N_ + n] = mean / (sqrtf(var) + 1e-5f);
    }
    return;
  }
  if (t >= 256) return;
  if (blk < 544) {
    int gid = (blk - 512) * 256 + t;
    int n = gid >> 4, h = gid & 15;
    float aq = 0.f, ak = 0.f;
#pragma unroll
    for (int i = 0; i < 16; ++i) {
      float ve = var_embed[n * 16 + i];
      aq += ve * q_w[i * 16 + h];
      ak += ve * k_w[i * 16 + h];
    }
    veq[gid] = aq;
    vek[gid] = ak;
  } else if (blk == 544) {
    if (t < 16) {
      int h = t;
      float Aq = 0.f, Bq = 0.f, Cq = 0.f, Ak = 0.f, Bk = 0.f, Ck = 0.f;
#pragma unroll
      for (int j = 0; j < 16; ++j) {
        float qw = q_w[(16 + j) * 16 + h];
        float kw = k_w[(16 + j) * 16 + h];
        Aq += temp_w[j] * qw; Bq += temp_w[16 + j] * qw; Cq += temp_b[j] * qw;
        Ak += temp_w[j] * kw; Bk += temp_w[16 + j] * kw; Ck += temp_b[j] * kw;
      }
      abc[h]      = Aq; abc[16 + h] = Bq; abc[32 + h] = Cq + q_b[h];
      abc[48 + h] = Ak; abc[64 + h] = Bk; abc[80 + h] = Ck + k_b[h];
    } else if (t == 16) {
      float aI = 0.f, bI = 0.f, cI = 0.f;
#pragma unroll
      for (int j = 0; j < 16; ++j) {
        float iw = imp_w[16 + j];
        aI += temp_w[j] * iw; bI += temp_w[16 + j] * iw; cI += temp_b[j] * iw;
      }
      abc[96] = aI; abc[97] = bI; abc[98] = cI + imp_b[0];
    }
  } else if (blk < 547) {
    int n = (blk - 545) * 256 + t;
    float a = 0.f;
#pragma unroll
    for (int i = 0; i < 16; ++i)
      a += var_embed[n * 16 + i] * imp_w[i];
    vei[n] = a;
  } else {
#pragma unroll
    for (int u = 0; u < 2; ++u) {
      int n = t + u * 256;
      float v[16], mx = -3e38f;
#pragma unroll
      for (int c = 0; c < 16; ++c) { v[c] = cs[n * 16 + c]; mx = fmaxf(mx, v[c]); }
      float s = 0.f;
#pragma unroll
      for (int c = 0; c < 16; ++c) { v[c] = expf(v[c] - mx); s += v[c]; }
      float inv = 1.f / s;
#pragma unroll
      for (int c = 0; c < 16; ++c) cw[n * 16 + c] = v[c] * inv;
    }
    if (t < 64) {
      float a = 0.f;
#pragma unroll 8
      for (int d = 0; d < 64; ++d) a += cp2_w[t * 64 + d];
      misc[t] = a;
      float vb = 0.f;
#pragma unroll 8
      for (int e = 0; e < 64; ++e) vb += vp_b[e] * cp1_w[e * 64 + t];
      misc[80 + t] = vb;
    }
    if (t == 0) {
      float bsum = 0.f;
      for (int d = 0; d < 64; ++d) bsum += cp2_b[d];
      misc[64] = bsum;
    }
#pragma unroll
    for (int u = 0; u < 4; ++u) {
      int i = t + u * 256;
      int c = i >> 6, d = i & 63;
      float a = 0.f;
#pragma unroll 8
      for (int e = 0; e < 64; ++e) a += vp_w[c * 64 + e] * cp1_w[e * 64 + d];
      misc[96 + i] = a;
    }
  }
}

// ---------------- 2. sim partials ----------------
__global__ __launch_bounds__(256) void k_sim(const float* __restrict__ nrm,
                                             float* __restrict__ simP) {
  __shared__ float As[32 * 64];
  __shared__ float Bs[32 * 64];
  int bx = blockIdx.x;
  int ks = bx >> 6, tile = bx & 63;
  int bi = tile & 7, bj = tile >> 3;
  int t = threadIdx.x, tx = t & 15, ty = t >> 4;
  float acc[4][4] = {};
  int k0 = ks * (L_ / KS_);
  for (int kt = 0; kt < (L_ / KS_) / 32; ++kt) {
    for (int e = t; e < 2048; e += 256) {
      int kk = e >> 6, i = e & 63;
      int krow = k0 + kt * 32 + kk;
      As[e] = nrm[krow * N_ + bi * 64 + i];
      Bs[e] = nrm[krow * N_ + bj * 64 + i];
    }
    __syncthreads();
#pragma unroll
    for (int kk = 0; kk < 32; ++kk) {
      float4 a = *(const float4*)(As + kk * 64 + ty * 4);
      float4 b = *(const float4*)(Bs + kk * 64 + tx * 4);
      float av[4] = {a.x, a.y, a.z, a.w};
      float bv[4] = {b.x, b.y, b.z, b.w};
#pragma unroll
      for (int i = 0; i < 4; ++i)
#pragma unroll
        for (int j = 0; j < 4; ++j)
          acc[i][j] += av[i] * bv[j];
    }
    __syncthreads();
  }
  float* outp = simP + (size_t)ks * (N_ * N_);
#pragma unroll
  for (int i = 0; i < 4; ++i) {
    int row = bi * 64 + ty * 4 + i;
    float4 o = {acc[i][0], acc[i][1], acc[i][2], acc[i][3]};
    *(float4*)(outp + row * N_ + bj * 64 + tx * 4) = o;
  }
}

// ---------------- 3. simred (0-255) + psum collapse (256-287) ----------------
__global__ __launch_bounds__(256) void k_simred(const float* __restrict__ simP,
                                                float* __restrict__ sim,
                                                const float* __restrict__ psum,
                                                const float* __restrict__ psq,
                                                float* __restrict__ psumR,
                                                float* __restrict__ psqR) {
  int t = threadIdx.x;
  if (blockIdx.x < 256) {
    int gid = blockIdx.x * 256 + t;
    float4 s = {0.f, 0.f, 0.f, 0.f};
#pragma unroll
    for (int ksi = 0; ksi < KS_; ++ksi) {
      float4 p = *(const float4*)(simP + (size_t)ksi * (N_ * N_) + gid * 4);
      s.x += p.x; s.y += p.y; s.z += p.z; s.w += p.w;
    }
    *(float4*)(sim + gid * 4) = s;
    return;
  }
  int tid = (blockIdx.x - 256) * 256 + t;   // [0, 8192)
  const float* src = (tid < 4096) ? psum : psq;
  float* dst = (tid < 4096) ? psumR : psqR;
  int id = tid & 4095;
  int b = id >> 9, n = id & 511;
  float a = 0.f;
#pragma unroll 8
  for (int c = 0; c < 512; ++c)
    a += src[((size_t)b * 512 + c) * N_ + n];
  dst[id] = a;
}

// ---------------- 4. topk radix (0-127) + rfinal-lite (128-143) ----------------
__global__ __launch_bounds__(256) void k_tf(
    const float* __restrict__ sim, int* __restrict__ idx_t,
    const float* __restrict__ psumR, const float* __restrict__ psqR,
    const float* __restrict__ veq, const float* __restrict__ vek,
    const float* __restrict__ abc, const float* __restrict__ vei,
    float* __restrict__ Q, float* __restrict__ Kv,
    float* __restrict__ imp, float* __restrict__ summary) {
  int t = threadIdx.x;
  if (blockIdx.x < 128) {
    int lane = t & 63, wv = t >> 6;
    int n = blockIdx.x * 4 + wv;
    unsigned sv[8];
#pragma unroll
    for (int u = 0; u < 8; ++u) {
      int idx = u * 64 + lane;
      float f = (idx == n) ? -3e38f : sim[n * N_ + idx];
      unsigned xb = __float_as_uint(f);
      sv[u] = (xb & 0x80000000u) ? ~xb : (xb | 0x80000000u);
    }
    unsigned thr = 0u;
#pragma unroll
    for (int b = 31; b >= 0; --b) {
      unsigned cand = thr | (1u << b);
      int cnt = 0;
#pragma unroll
      for (int u = 0; u < 8; ++u)
        cnt += __popcll(__ballot(sv[u] >= cand));
      if (cnt >= TK_) thr = cand;
    }
    int cgt = 0;
#pragma unroll
    for (int u = 0; u < 8; ++u)
      cgt += __popcll(__ballot(sv[u] > thr));
    int need = TK_ - cgt;
    unsigned long long lt_mask = (lane == 0) ? 0ull : (~0ull >> (64 - lane));
    int written = 0, tie_seen = 0;
#pragma unroll
    for (int u = 0; u < 8; ++u) {
      bool gt = sv[u] > thr;
      bool eq = sv[u] == thr;
      unsigned long long me = __ballot(eq);
      bool sel = gt || (eq && (tie_seen + __popcll(me & lt_mask)) < need);
      unsigned long long ms = __ballot(sel);
      int pos = written + __popcll(ms & lt_mask);
      if (sel) idx_t[pos * N_ + n] = u * 64 + lane;
      written += __popcll(ms);
      tie_seen += __popcll(me);
    }
    return;
  }
  int gid = (blockIdx.x - 128) * 256 + t;
  int b = gid >> 9, n = gid & 511;
  float s  = psumR[gid];
  float ss = psqR[gid];
  float mean = s * (1.f / L_);
  float var  = fmaxf((ss - s * mean) * (1.f / (L_ - 1)), 0.f);
  float stdv = sqrtf(var + 1e-5f);
  summary[b * N_ + n] = mean;
#pragma unroll
  for (int h = 0; h < 16; ++h) {
    Q[(b * N_ + n) * 16 + h]  = veq[n * 16 + h] + mean * abc[h]      + stdv * abc[16 + h] + abc[32 + h];
    Kv[(b * N_ + n) * 16 + h] = vek[n * 16 + h] + mean * abc[48 + h] + stdv * abc[64 + h] + abc[80 + h];
  }
  imp[b * N_ + n] = sigmoidf_(vei[n] + mean * abc[96] + stdv * abc[97] + abc[98]);
}

// ---------------- 5. weight prep + ct partials ----------------
__global__ __launch_bounds__(256) void k_wprep(const float* __restrict__ gate_w,
                                               const float* __restrict__ fus_w,
                                               const float* __restrict__ cw,
                                               const float* __restrict__ misc,
                                               const float* __restrict__ summ,
                                               const float* __restrict__ cg_w,
                                               const float* __restrict__ cg_b,
                                               short* __restrict__ wt_gate,
                                               short* __restrict__ wt_fus,
                                               short* __restrict__ w2t,
                                               short* __restrict__ cwb,
                                               float* __restrict__ ctP) {
  __shared__ float tile[32][33];
  __shared__ float ssum[8][64];
  int blk = blockIdx.x, t = threadIdx.x;
  if (blk < 512) {
    const float* W = (blk < 256) ? gate_w : fus_w;
    short* Wt = (blk < 256) ? wt_gate : wt_fus;
    int ldd = (blk < 256) ? 1024 : 512;
    int b2 = blk & 255;
    int bk = b2 >> 4, bn = b2 & 15;
    int c = t & 31, r = t >> 5;
    for (int rr = r; rr < 32; rr += 8)
      tile[rr][c] = W[(size_t)(bk * 32 + rr) * 512 + bn * 32 + c];
    __syncthreads();
    for (int rr = r; rr < 32; rr += 8)
      Wt[(size_t)(bn * 32 + rr) * ldd + bk * 32 + c] = f2bf(tile[c][rr]);
  } else if (blk < 544) {
    int gid = (blk - 512) * 256 + t;
    int c = gid >> 9, n = gid & 511;
    float a = 0.f;
    for (int m = 0; m < 512; ++m)
      a += cw[m * 16 + c] * gate_w[(size_t)(512 + m) * 512 + n];
    wt_gate[(size_t)n * 1024 + 512 + c] = f2bf(a);
    wt_gate[(size_t)n * 1024 + 528 + c] = 0;
    wt_gate[(size_t)n * 1024 + 544 + c] = 0;   // zero tail so BK-64 tile 8 is exact
    wt_gate[(size_t)n * 1024 + 560 + c] = 0;
  } else if (blk < 672) {
    int gid = (blk - 544) * 256 + t;
    int d = gid >> 9, m = gid & 511;
    float a = 0.f;
#pragma unroll
    for (int c = 0; c < 16; ++c)
      a += cw[m * 16 + c] * misc[96 + c * 64 + d];
    w2t[d * 512 + m] = f2bf(a);
  } else if (blk < 736) {
    int gid = (blk - 672) * 256 + t;
    int n = gid >> 5, kk = gid & 31;
    cwb[gid] = (kk < 16) ? f2bf(cw[n * 16 + kk]) : (short)0;
  } else {
    int bx = blk - 736;
    int oc = bx & 31;
    int nc = bx >> 5;
    int n0 = nc * 64;
    for (int e = t; e < 512; e += 256)
      ssum[e >> 6][e & 63] = summ[(e >> 6) * 512 + n0 + (e & 63)];
    __syncthreads();
    int b = t >> 5, ol = t & 31;
    int o = oc * 32 + ol;
    float acc = (nc == 0) ? cg_b[o] : 0.f;
#pragma unroll 8
    for (int k = 0; k < 64; ++k)
      acc += ssum[b][k] * cg_w[(size_t)(n0 + k) * 1024 + o];
    ctP[(nc * 8 + b) * 1024 + o] = acc;
  }
}

// ---------------- 6. ctp (0-31) + attn (32-1055) + xcp (1056-1311) ----------------
__global__ __launch_bounds__(256) void k_caxc(const float* __restrict__ ctP,
                                              const float* __restrict__ cp1_w,
                                              const float* __restrict__ cp1_b,
                                              const float* __restrict__ misc,
                                              float* __restrict__ ctp,
                                              const float* __restrict__ Q,
                                              const float* __restrict__ Kv,
                                              const int* __restrict__ idx_t,
                                              short* __restrict__ At,
                                              const short* __restrict__ xbf,
                                              const short* __restrict__ w2t,
                                              float* __restrict__ xcp) {
  __shared__ float cts[256];
  __shared__ short rowbuf[4][512];
  __shared__ __align__(16) short As[2][64 * 32];
  __shared__ __align__(16) short Bs[2][64 * 32];
  int blk = blockIdx.x, t = threadIdx.x;
  if (blk < 32) {
    int row0 = blk * 4;
    int b = row0 >> 4, c0 = row0 & 15;
    {
      int idx = (c0 + (t >> 6)) * 64 + (t & 63);
      float a = 0.f;
#pragma unroll
      for (int p = 0; p < 8; ++p) a += ctP[(p * 8 + b) * 1024 + idx];
      cts[t] = a;
    }
    __syncthreads();
    int lr = t >> 6, d2 = t & 63;
    float a = cp1_b[d2] + misc[80 + d2];
#pragma unroll 8
    for (int d = 0; d < 64; ++d) a += cts[lr * 64 + d] * cp1_w[d * 64 + d2];
    ctp[(row0 + lr) * 64 + d2] = a;
  } else if (blk < 32 + 1024) {
    int w = t >> 6, j = t & 63;
    int bn = (blk - 32) * 4 + w;
    int b = bn >> 9, n = bn & (N_ - 1);
    ((int4*)rowbuf[w])[j] = int4{0, 0, 0, 0};
    float s = -3e38f;
    int m = 0;
    if (j < TK_) {
      m = idx_t[j * N_ + n];
      const float* qp = Q + (b * N_ + n) * H_;
      const float* kp = Kv + (b * N_ + m) * H_;
      float a = 0.f;
#pragma unroll
      for (int h = 0; h < H_; ++h) a += qp[h] * kp[h];
      s = a * 0.25f;
    }
    float mx = s;
#pragma unroll
    for (int o = 32; o > 0; o >>= 1) mx = fmaxf(mx, __shfl_xor(mx, o));
    float e = (j < TK_) ? expf(s - mx) : 0.f;
    float sum = e;
#pragma unroll
    for (int o = 32; o > 0; o >>= 1) sum += __shfl_xor(sum, o);
    __syncthreads();
    if (j < TK_) rowbuf[w][m] = f2bf(e / sum);
    __syncthreads();
    ((int4*)(At + (size_t)bn * 512))[j] = ((int4*)rowbuf[w])[j];
  } else {
    int lane = t & 63, w = t >> 6;
    int lo = lane & 15, hi = lane >> 4;
    int row0 = (blk - 1056) * 64;
    f32x4 acc[4] = {};
    int rA = t >> 2, cA = (t & 3) ^ ((rA >> 1) & 3);
    const short* srcA = xbf + (size_t)(row0 + rA) * 512 + cA * 8;
    const short* srcB = w2t + (size_t)rA * 512 + cA * 8;
    int gl = (lo >> 1) & 3;
    int foff = (lo * 4 + (hi ^ gl)) * 8;
    gload16(srcA, As[0] + t * 8);
    gload16(srcB, Bs[0] + t * 8);
    __syncthreads();
    int cur = 0;
    for (int kt = 0; kt < 16; ++kt) {
      if (kt < 15) {
        gload16(srcA + (kt + 1) * 32, As[cur ^ 1] + t * 8);
        gload16(srcB + (kt + 1) * 32, Bs[cur ^ 1] + t * 8);
      }
      bf16x8 b = *(const bf16x8*)(Bs[cur] + (w * 64) * 8 + foff);
#pragma unroll
      for (int m = 0; m < 4; ++m) {
        bf16x8 a = *(const bf16x8*)(As[cur] + (m * 64) * 8 + foff);
        acc[m] = __builtin_amdgcn_mfma_f32_16x16x32_bf16(a, b, acc[m], 0, 0, 0);
      }
      __syncthreads();
      cur ^= 1;
    }
#pragma unroll
    for (int m = 0; m < 4; ++m)
#pragma unroll
      for (int j = 0; j < 4; ++j) {
        int row = row0 + m * 16 + hi * 4 + j;
        int col = w * 16 + lo;
        xcp[(size_t)row * 64 + col] = acc[m][j];
      }
  }
}

// ---------------- 7. rgemm BK=64 XCD-swizzled (0-511) + s2 shuffle-free (512-1023) ----------------
__global__ __launch_bounds__(512) void k_sg(const short* __restrict__ xbf,
                                            const short* __restrict__ At,
                                            const float* __restrict__ imp,
                                            short* __restrict__ abuf,
                                            const float* __restrict__ xcp,
                                            const float* __restrict__ ctp,
                                            const float* __restrict__ misc) {
  __shared__ __align__(16) short As[2][128 * 64];
  __shared__ __align__(16) short Bs[2][128 * 64];
  int blk = blockIdx.x, t = threadIdx.x;
  int lane = t & 63, w = t >> 6;
  if (blk < 512) {
    int vid = ((blk & 7) << 6) | (blk >> 3);   // bijective XCD swizzle
    int lo = lane & 15, hi = lane >> 4;
    int b = vid >> 6;
    int tile = vid & 63;
    int bm = tile >> 2, bn = tile & 3;
    int row0 = b * L_ + bm * 128, n0 = bn * 128;
    int wm = w >> 2, wn = w & 3;
    f32x4 acc[4][2] = {};
    int p0 = t, p1 = t + 512;
    int r0s = p0 >> 3, c0s = (p0 & 7) ^ (r0s & 7);
    int r1s = p1 >> 3, c1s = (p1 & 7) ^ (r1s & 7);
    const short* sA0 = xbf + (size_t)(row0 + r0s) * 512 + c0s * 8;
    const short* sA1 = xbf + (size_t)(row0 + r1s) * 512 + c1s * 8;
    const short* sB0 = At + ((size_t)b * N_ + n0 + r0s) * 512 + c0s * 8;
    const short* sB1 = At + ((size_t)b * N_ + n0 + r1s) * 512 + c1s * 8;
    int l7 = lo & 7;
    int sw0 = (hi ^ l7) * 8;
    int sw1 = ((hi + 4) ^ l7) * 8;
    gload16(sA0, As[0] + p0 * 8);
    gload16(sA1, As[0] + p1 * 8);
    gload16(sB0, Bs[0] + p0 * 8);
    gload16(sB1, Bs[0] + p1 * 8);
    __syncthreads();
    int cur = 0;
    for (int i = 0; i < 8; ++i) {
      if (i < 7) {
        gload16(sA0 + (i + 1) * 64, As[cur ^ 1] + p0 * 8);
        gload16(sA1 + (i + 1) * 64, As[cur ^ 1] + p1 * 8);
        gload16(sB0 + (i + 1) * 64, Bs[cur ^ 1] + p0 * 8);
        gload16(sB1 + (i + 1) * 64, Bs[cur ^ 1] + p1 * 8);
      }
#pragma unroll
      for (int s = 0; s < 2; ++s) {
        int sw = s ? sw1 : sw0;
        bf16x8 a[4], bb[2];
#pragma unroll
        for (int m = 0; m < 4; ++m)
          a[m] = *(const bf16x8*)(As[cur] + (wm * 64 + m * 16 + lo) * 64 + sw);
#pragma unroll
        for (int n = 0; n < 2; ++n)
          bb[n] = *(const bf16x8*)(Bs[cur] + (wn * 32 + n * 16 + lo) * 64 + sw);
#pragma unroll
        for (int m = 0; m < 4; ++m)
#pragma unroll
          for (int n = 0; n < 2; ++n)
            acc[m][n] = __builtin_amdgcn_mfma_f32_16x16x32_bf16(a[m], bb[n], acc[m][n], 0, 0, 0);
      }
      __syncthreads();
      cur ^= 1;
    }
#pragma unroll
    for (int m = 0; m < 4; ++m) {
      int rbase = row0 + wm * 64 + m * 16 + hi * 4;
#pragma unroll
      for (int j = 0; j < 4; ++j) {
        int row = rbase + j;
#pragma unroll
        for (int n = 0; n < 2; ++n) {
          int col = n0 + wn * 32 + n * 16 + lo;
          float iv = imp[b * N_ + col];
          float xv = bf2f(xbf[(size_t)row * 512 + col]);
          abuf[(size_t)row * 1024 + col] = f2bf(iv * acc[m][n][j] + (1.f - iv) * xv);
        }
      }
    }
  } else {
    // s2: thread-per-(row,c), LDS-staged, no cross-lane ops
    float* xcps = (float*)As;               // 32 x 65 floats
    float* ctps = (float*)Bs;               // 16 x 65 floats
    float* cp2sd = ((float*)Bs) + 1100;     // 65 floats
    int row0 = (blk - 512) * 32;
    int b = row0 >> 11;
    for (int e = t; e < 32 * 64; e += 512)
      xcps[(e >> 6) * 65 + (e & 63)] = xcp[(size_t)(row0 + (e >> 6)) * 64 + (e & 63)];
    for (int e = t; e < 16 * 64; e += 512)
      ctps[(e >> 6) * 65 + (e & 63)] = ctp[b * 1024 + e];
    if (t < 65) cp2sd[t] = misc[t];
    __syncthreads();
    int r = t >> 4, c = t & 15;
    const float* xr = xcps + r * 65;
    const float* cc = ctps + c * 65;
    float acc = 0.f;
#pragma unroll 8
    for (int d = 0; d < 64; ++d) {
      float u = cc[d] + xr[d];
      float g = 0.5f * u * (1.f + erff(u * 0.70710678118654752f));
      acc += g * cp2sd[d];
    }
    int row = row0 + r;
    abuf[(size_t)row * 1024 + 512 + c] = f2bf(acc + cp2sd[64]);
    abuf[(size_t)row * 1024 + 528 + c] = 0;
    abuf[(size_t)row * 1024 + 544 + c] = 0;   // zero A-tail: gate BK-64 tile 8 reads cols 512-575
    abuf[(size_t)row * 1024 + 560 + c] = 0;
  }
}

// ---------------- 8. gate GEMM BK=64 (XCD-swizzled, K=576 w/ zero tail) ----------------
__global__ __launch_bounds__(512) void k_gemm_gate(const short* __restrict__ abuf,
                                                   const short* __restrict__ wt,
                                                   const short* __restrict__ cwb,
                                                   const float* __restrict__ gate_b,
                                                   short* __restrict__ fused_bf) {
  __shared__ __align__(16) short As[2][128 * 64];
  __shared__ __align__(16) short Bs[2][128 * 64];
  int t = threadIdx.x, lane = t & 63, w = t >> 6;
  int lo = lane & 15, hi = lane >> 4;
  int vid = ((blockIdx.x & 7) << 6) | (blockIdx.x >> 3);
  int bm = vid >> 2, bn = vid & 3;
  int row0 = bm * 128, n0 = bn * 128;
  int wm = w >> 2, wn = w & 3;
  f32x4 acc[4][2] = {};
  f32x4 acc2[4][2] = {};
  // prologue (BK-32 layout): A s2-tile (cols 512-543) + cwb
  int r32 = t >> 2, c32 = (t & 3) ^ ((r32 >> 1) & 3);
  int gl32 = (lo >> 1) & 3;
  int foff32 = (lo * 4 + (hi ^ gl32)) * 8;
  gload16(abuf + (size_t)(row0 + r32) * 1024 + 512 + c32 * 8, As[0] + t * 8);
  gload16(cwb + (size_t)(n0 + r32) * 32 + c32 * 8, Bs[0] + t * 8);
  // main BK-64 pointers
  int p0 = t, p1 = t + 512;
  int r0s = p0 >> 3, c0s = (p0 & 7) ^ (r0s & 7);
  int r1s = p1 >> 3, c1s = (p1 & 7) ^ (r1s & 7);
  const short* sA0 = abuf + (size_t)(row0 + r0s) * 1024 + c0s * 8;
  const short* sA1 = abuf + (size_t)(row0 + r1s) * 1024 + c1s * 8;
  const short* sB0 = wt + (size_t)(n0 + r0s) * 1024 + c0s * 8;
  const short* sB1 = wt + (size_t)(n0 + r1s) * 1024 + c1s * 8;
  int l7 = lo & 7;
  int sw0 = (hi ^ l7) * 8;
  int sw1 = ((hi + 4) ^ l7) * 8;
  // main tile 0 into buffer 1
  gload16(sA0, As[1] + p0 * 8);
  gload16(sA1, As[1] + p1 * 8);
  gload16(sB0, Bs[1] + p0 * 8);
  gload16(sB1, Bs[1] + p1 * 8);
  __syncthreads();
  {
    bf16x8 a[4], bb[2];
#pragma unroll
    for (int m = 0; m < 4; ++m)
      a[m] = *(const bf16x8*)(As[0] + (wm * 64 + m * 16) * 32 + foff32);
#pragma unroll
    for (int n = 0; n < 2; ++n)
      bb[n] = *(const bf16x8*)(Bs[0] + (wn * 32 + n * 16) * 32 + foff32);
#pragma unroll
    for (int m = 0; m < 4; ++m)
#pragma unroll
      for (int n = 0; n < 2; ++n)
        acc2[m][n] = __builtin_amdgcn_mfma_f32_16x16x32_bf16(a[m], bb[n], acc2[m][n], 0, 0, 0);
  }
  __syncthreads();
  int cur = 1;
  for (int i = 0; i < 9; ++i) {
    if (i < 8) {
      gload16(sA0 + (i + 1) * 64, As[cur ^ 1] + p0 * 8);
      gload16(sA1 + (i + 1) * 64, As[cur ^ 1] + p1 * 8);
      gload16(sB0 + (i + 1) * 64, Bs[cur ^ 1] + p0 * 8);
      gload16(sB1 + (i + 1) * 64, Bs[cur ^ 1] + p1 * 8);
    }
#pragma unroll
    for (int s = 0; s < 2; ++s) {
      int sw = s ? sw1 : sw0;
      bf16x8 a[4], bb[2];
#pragma unroll
      for (int m = 0; m < 4; ++m)
        a[m] = *(const bf16x8*)(As[cur] + (wm * 64 + m * 16 + lo) * 64 + sw);
#pragma unroll
      for (int n = 0; n < 2; ++n)
        bb[n] = *(const bf16x8*)(Bs[cur] + (wn * 32 + n * 16 + lo) * 64 + sw);
#pragma unroll
      for (int m = 0; m < 4; ++m)
#pragma unroll
        for (int n = 0; n < 2; ++n)
          acc[m][n] = __builtin_amdgcn_mfma_f32_16x16x32_bf16(a[m], bb[n], acc[m][n], 0, 0, 0);
    }
    __syncthreads();
    cur ^= 1;
  }
#pragma unroll
  for (int m = 0; m < 4; ++m) {
    int rbase = row0 + wm * 64 + m * 16 + hi * 4;
#pragma unroll
    for (int j = 0; j < 4; ++j) {
      int row = rbase + j;
#pragma unroll
      for (int n = 0; n < 2; ++n) {
        int col = n0 + wn * 32 + n * 16 + lo;
        float g = sigmoidf_(acc[m][n][j] + gate_b[col]);
        float ringv = bf2f(abuf[(size_t)row * 1024 + col]);
        fused_bf[(size_t)row * 512 + col] = f2bf(g * ringv + (1.f - g) * acc2[m][n][j]);
      }
    }
  }
}

// ---------------- 9. fus GEMM (XCD-swizzled, pipelined) + residual + LayerNorm ----------------
__global__ __launch_bounds__(512) void k_gemm_fus(const short* __restrict__ fused_bf,
                                                  const short* __restrict__ wtf,
                                                  const float* __restrict__ x,
                                                  const float* __restrict__ fus_b,
                                                  const float* __restrict__ ln_g,
                                                  const float* __restrict__ ln_b,
                                                  float* __restrict__ out) {
  __shared__ __align__(16) short As[2][64 * 32];
  __shared__ __align__(16) short Bs[2][512 * 32];
  __shared__ float Ssh[8][64], Qsh[8][64];
  __shared__ float mus[64], rss[64];
  int t = threadIdx.x, lane = t & 63, w = t >> 6;
  int lo = lane & 15, hi = lane >> 4;
  int vid = ((blockIdx.x & 7) << 5) | (blockIdx.x >> 3);
  int row0 = vid * 64;
  f32x4 acc[4][4] = {};
  int pA = w * 64 + lane;
  int rA = pA >> 2, cA = (pA & 3) ^ ((rA >> 1) & 3);
  const short* srcA = fused_bf + (size_t)(row0 + rA) * 512 + cA * 8;
  int rB[4], cB[4];
  const short* srcB[4];
#pragma unroll
  for (int q = 0; q < 4; ++q) {
    int pB = w * 256 + q * 64 + lane;
    rB[q] = pB >> 2; cB[q] = (pB & 3) ^ ((rB[q] >> 1) & 3);
    srcB[q] = wtf + (size_t)rB[q] * 512 + cB[q] * 8;
  }
  int gl = (lo >> 1) & 3;
  int foff = (lo * 4 + (hi ^ gl)) * 8;
  if (w < 4) gload16(srcA, As[0] + pA * 8);
#pragma unroll
  for (int q = 0; q < 4; ++q)
    gload16(srcB[q], Bs[0] + (w * 256 + q * 64) * 8);
  __syncthreads();
  int cur = 0;
  for (int i = 0; i < 16; ++i) {
    if (i < 15) {
      int kt = i + 1;
      if (w < 4) gload16(srcA + kt * 32, As[cur ^ 1] + pA * 8);
#pragma unroll
      for (int q = 0; q < 4; ++q)
        gload16(srcB[q] + kt * 32, Bs[cur ^ 1] + (w * 256 + q * 64) * 8);
    }
    bf16x8 a[4], b[4];
#pragma unroll
    for (int m = 0; m < 4; ++m)
      a[m] = *(const bf16x8*)(As[cur] + (m * 64) * 8 + foff);
#pragma unroll
    for (int n = 0; n < 4; ++n)
      b[n] = *(const bf16x8*)(Bs[cur] + (w * 256 + n * 64) * 8 + foff);
#pragma unroll
    for (int m = 0; m < 4; ++m)
#pragma unroll
      for (int n = 0; n < 4; ++n)
        acc[m][n] = __builtin_amdgcn_mfma_f32_16x16x32_bf16(a[m], b[n], acc[m][n], 0, 0, 0);
    __syncthreads();
    cur ^= 1;
  }
#pragma unroll
  for (int m = 0; m < 4; ++m) {
#pragma unroll
    for (int j = 0; j < 4; ++j) {
      int rl = m * 16 + hi * 4 + j;
      int row = row0 + rl;
      float ps = 0.f, pq = 0.f;
#pragma unroll
      for (int n = 0; n < 4; ++n) {
        int col = w * 64 + n * 16 + lo;
        float h = acc[m][n][j] + fus_b[col] + x[(size_t)row * 512 + col];
        acc[m][n][j] = h;
        ps += h; pq += h * h;
      }
#pragma unroll
      for (int o = 1; o < 16; o <<= 1) {
        ps += __shfl_xor(ps, o);
        pq += __shfl_xor(pq, o);
      }
      if (lo == 0) { Ssh[w][rl] = ps; Qsh[w][rl] = pq; }
    }
  }
  __syncthreads();
  if (t < 64) {
    float s = 0.f, q = 0.f;
#pragma unroll
    for (int ww = 0; ww < 8; ++ww) { s += Ssh[ww][t]; q += Qsh[ww][t]; }
    float mu = s * (1.f / N_);
    float var = q * (1.f / N_) - mu * mu;
    mus[t] = mu;
    rss[t] = rsqrtf(fmaxf(var, 0.f) + 1e-5f);
  }
  __syncthreads();
#pragma unroll
  for (int m = 0; m < 4; ++m) {
#pragma unroll
    for (int j = 0; j < 4; ++j) {
      int rl = m * 16 + hi * 4 + j;
      int row = row0 + rl;
      float mu = mus[rl], rs = rss[rl];
#pragma unroll
      for (int n = 0; n < 4; ++n) {
        int col = w * 64 + n * 16 + lo;
        out[(size_t)row * 512 + col] = (acc[m][n][j] - mu) * rs * ln_g[col] + ln_b[col];
      }
    }
  }
}

extern "C" void kernel_launch(void* const* d_in, const int* in_sizes, int n_in,
                              void* d_out, int out_size, void* d_ws, size_t ws_size,
                              hipStream_t stream) {
  (void)in_sizes; (void)n_in; (void)out_size; (void)ws_size;
  const float* x         = (const float*)d_in[0];
  const float* var_embed = (const float*)d_in[1];
  const float* temp_w    = (const float*)d_in[2];
  const float* temp_b    = (const float*)d_in[3];
  const float* q_w       = (const float*)d_in[4];
  const float* q_b       = (const float*)d_in[5];
  const float* k_w       = (const float*)d_in[6];
  const float* k_b       = (const float*)d_in[7];
  const float* imp_w     = (const float*)d_in[8];
  const float* imp_b     = (const float*)d_in[9];
  const float* cluster   = (const float*)d_in[10];
  const float* vp_w      = (const float*)d_in[11];
  const float* vp_b      = (const float*)d_in[12];
  const float* cp1_w     = (const float*)d_in[13];
  const float* cp1_b     = (const float*)d_in[14];
  const float* cp2_w     = (const float*)d_in[15];
  const float* cp2_b     = (const float*)d_in[16];
  const float* cg_w      = (const float*)d_in[17];
  const float* cg_b      = (const float*)d_in[18];
  const float* gate_w    = (const float*)d_in[19];
  const float* gate_b    = (const float*)d_in[20];
  const float* fus_w     = (const float*)d_in[21];
  const float* fus_b     = (const float*)d_in[22];
  const float* ln_g      = (const float*)d_in[23];
  const float* ln_b      = (const float*)d_in[24];
  float* out = (float*)d_out;
  float* ws  = (float*)d_ws;

  float* normed = ws + 0;                 // 4 MB (xcp reuses)
  int*   idx_t  = (int*)(ws + 1310720);
  float* Qb     = ws + 1335296;
  float* Kb     = ws + 1400832;
  float* impb   = ws + 1466368;
  float* summ   = ws + 1470464;
  float* cw     = ws + 1658880;
  float* ctp    = ws + 1675264;
  float* misc   = ws + 1683456;
  short* w2t    = (short*)(ws + 1693696);
  short* cwb    = (short*)(ws + 1710080);
  short* abuf     = (short*)(ws + 1720320);   // 32 MB
  short* fused_bf = (short*)(ws + 10108928);  // 16 MB (also xbf)
  short* wt_gate  = (short*)(ws + 14303232);
  short* wt_fus   = (short*)(ws + 14565376);
  float* ctP      = ws + 15220736;
  short* At       = (short*)(ws + 15286272);  // 4 MB
  float* sim      = ws + 16334848;
  float* veq      = ws + 16596992;
  float* vek      = ws + 16605184;
  float* abc      = ws + 16613376;
  float* vei      = ws + 16613504;
  float* psum     = ws + 17000000;            // 8*512*512
  float* psq      = ws + 19200000;
  float* psumR    = ws + 21400000;
  float* psqR     = ws + 21410000;
  float* simP = (float*)abuf;   // dead after k_simred
  float* xcp  = normed;
  short* xbf  = fused_bf;

  k_pre<<<548, 512, 0, stream>>>(x, var_embed, temp_w, temp_b, q_w, q_b, k_w, k_b,
                                 imp_w, imp_b, cluster, cp2_w, cp2_b, vp_b, vp_w,
                                 cp1_w, normed, psum, psq, xbf, veq, vek, abc, vei,
                                 cw, misc);
  k_sim<<<64 * KS_, 256, 0, stream>>>(normed, simP);
  k_simred<<<288, 256, 0, stream>>>(simP, sim, psum, psq, psumR, psqR);
  k_tf<<<144, 256, 0, stream>>>(sim, idx_t, psumR, psqR, veq, vek, abc, vei,
                                Qb, Kb, impb, summ);
  k_wprep<<<992, 256, 0, stream>>>(gate_w, fus_w, cw, misc, summ, cg_w, cg_b,
                                   wt_gate, wt_fus, w2t, cwb, ctP);
  k_caxc<<<1312, 256, 0, stream>>>(ctP, cp1_w, cp1_b, misc, ctp, Qb, Kb, idx_t,
                                   At, xbf, w2t, xcp);
  k_sg<<<1024, 512, 0, stream>>>(xbf, At, impb, abuf, xcp, ctp, misc);
  k_gemm_gate<<<512, 512, 0, stream>>>(abuf, wt_gate, cwb, gate_b, fused_bf);
  k_gemm_fus<<<256, 512, 0, stream>>>(fused_bf, wt_fus, x, fus_b, ln_g, ln_b, out);
}

// Round 22
// 188.389 us; speedup vs baseline: 1.0134x; 1.0134x over previous
//
#include <hip/hip_runtime.h>

#define B_ 8
#define L_ 2048
#define N_ 512
#define H_ 16
#define C_ 16
#define D_ 64
#define TK_ 45
#define KS_ 16

#define WAITV(N) asm volatile("s_waitcnt vmcnt(" #N ")" ::: "memory")
#define SBAR()   asm volatile("s_barrier" ::: "memory")

typedef __attribute__((ext_vector_type(8))) short bf16x8;
typedef __attribute__((ext_vector_type(4))) float f32x4;

__device__ __forceinline__ float sigmoidf_(float v) { return 1.f / (1.f + expf(-v)); }

__device__ __forceinline__ short f2bf(float f) {
  union { float f; unsigned u; } v; v.f = f;
  unsigned r = (v.u + 0x7fffu + ((v.u >> 16) & 1u)) >> 16;
  return (short)r;
}
__device__ __forceinline__ float bf2f(short s) {
  union { unsigned u; float f; } v; v.u = ((unsigned)(unsigned short)s) << 16;
  return v.f;
}
__device__ __forceinline__ void gload16(const void* g, void* l) {
  __builtin_amdgcn_global_load_lds((const __attribute__((address_space(1))) unsigned int*)g,
                                   (__attribute__((address_space(3))) unsigned int*)l, 16, 0, 0);
}

// ---------------- 1. single-pass x (0-511) + VE (512-543) + ABC (544)
//                   + vei (545-546) + cwmisc (547) ----------------
__global__ __launch_bounds__(512) void k_pre(const float* __restrict__ x,
                                             const float* __restrict__ var_embed,
                                             const float* __restrict__ temp_w,
                                             const float* __restrict__ temp_b,
                                             const float* __restrict__ q_w,
                                             const float* __restrict__ q_b,
                                             const float* __restrict__ k_w,
                                             const float* __restrict__ k_b,
                                             const float* __restrict__ imp_w,
                                             const float* __restrict__ imp_b,
                                             const float* __restrict__ cs,
                                             const float* __restrict__ cp2_w,
                                             const float* __restrict__ cp2_b,
                                             const float* __restrict__ vp_b,
                                             const float* __restrict__ vp_w,
                                             const float* __restrict__ cp1_w,
                                             float* __restrict__ normed,
                                             float* __restrict__ psum,
                                             float* __restrict__ psq,
                                             short* __restrict__ xbf,
                                             float* __restrict__ veq,
                                             float* __restrict__ vek,
                                             float* __restrict__ abc,
                                             float* __restrict__ vei,
                                             float* __restrict__ cw,
                                             float* __restrict__ misc) {
  int blk = blockIdx.x, t = threadIdx.x;
  if (blk < 512) {
    int l0 = blk * 4;
    int n = t;
    float row_s[4] = {}, row_ss[4] = {};
#pragma unroll
    for (int b = 0; b < B_; ++b) {
      float bs = 0.f, bss = 0.f;
#pragma unroll
      for (int r = 0; r < 4; ++r) {
        float v = x[((size_t)b * L_ + l0 + r) * N_ + n];
        bs += v; bss += v * v;
        row_s[r] += v; row_ss[r] += v * v;
        xbf[((size_t)b * L_ + l0 + r) * N_ + n] = f2bf(v);
      }
      psum[((size_t)b * 512 + blk) * N_ + n] = bs;
      psq [((size_t)b * 512 + blk) * N_ + n] = bss;
    }
#pragma unroll
    for (int r = 0; r < 4; ++r) {
      float mean = row_s[r] * (1.f / B_);
      float var  = fmaxf((row_ss[r] - row_s[r] * mean) * (1.f / (B_ - 1)), 0.f);
      normed[(l0 + r) * N_ + n] = mean / (sqrtf(var) + 1e-5f);
    }
    return;
  }
  if (t >= 256) return;
  if (blk < 544) {
    int gid = (blk - 512) * 256 + t;
    int n = gid >> 4, h = gid & 15;
    float aq = 0.f, ak = 0.f;
#pragma unroll
    for (int i = 0; i < 16; ++i) {
      float ve = var_embed[n * 16 + i];
      aq += ve * q_w[i * 16 + h];
      ak += ve * k_w[i * 16 + h];
    }
    veq[gid] = aq;
    vek[gid] = ak;
  } else if (blk == 544) {
    if (t < 16) {
      int h = t;
      float Aq = 0.f, Bq = 0.f, Cq = 0.f, Ak = 0.f, Bk = 0.f, Ck = 0.f;
#pragma unroll
      for (int j = 0; j < 16; ++j) {
        float qw = q_w[(16 + j) * 16 + h];
        float kw = k_w[(16 + j) * 16 + h];
        Aq += temp_w[j] * qw; Bq += temp_w[16 + j] * qw; Cq += temp_b[j] * qw;
        Ak += temp_w[j] * kw; Bk += temp_w[16 + j] * kw; Ck += temp_b[j] * kw;
      }
      abc[h]      = Aq; abc[16 + h] = Bq; abc[32 + h] = Cq + q_b[h];
      abc[48 + h] = Ak; abc[64 + h] = Bk; abc[80 + h] = Ck + k_b[h];
    } else if (t == 16) {
      float aI = 0.f, bI = 0.f, cI = 0.f;
#pragma unroll
      for (int j = 0; j < 16; ++j) {
        float iw = imp_w[16 + j];
        aI += temp_w[j] * iw; bI += temp_w[16 + j] * iw; cI += temp_b[j] * iw;
      }
      abc[96] = aI; abc[97] = bI; abc[98] = cI + imp_b[0];
    }
  } else if (blk < 547) {
    int n = (blk - 545) * 256 + t;
    float a = 0.f;
#pragma unroll
    for (int i = 0; i < 16; ++i)
      a += var_embed[n * 16 + i] * imp_w[i];
    vei[n] = a;
  } else {
#pragma unroll
    for (int u = 0; u < 2; ++u) {
      int n = t + u * 256;
      float v[16], mx = -3e38f;
#pragma unroll
      for (int c = 0; c < 16; ++c) { v[c] = cs[n * 16 + c]; mx = fmaxf(mx, v[c]); }
      float s = 0.f;
#pragma unroll
      for (int c = 0; c < 16; ++c) { v[c] = expf(v[c] - mx); s += v[c]; }
      float inv = 1.f / s;
#pragma unroll
      for (int c = 0; c < 16; ++c) cw[n * 16 + c] = v[c] * inv;
    }
    if (t < 64) {
      float a = 0.f;
#pragma unroll 8
      for (int d = 0; d < 64; ++d) a += cp2_w[t * 64 + d];
      misc[t] = a;
      float vb = 0.f;
#pragma unroll 8
      for (int e = 0; e < 64; ++e) vb += vp_b[e] * cp1_w[e * 64 + t];
      misc[80 + t] = vb;
    }
    if (t == 0) {
      float bsum = 0.f;
      for (int d = 0; d < 64; ++d) bsum += cp2_b[d];
      misc[64] = bsum;
    }
#pragma unroll
    for (int u = 0; u < 4; ++u) {
      int i = t + u * 256;
      int c = i >> 6, d = i & 63;
      float a = 0.f;
#pragma unroll 8
      for (int e = 0; e < 64; ++e) a += vp_w[c * 64 + e] * cp1_w[e * 64 + d];
      misc[96 + i] = a;
    }
  }
}

// ---------------- 2. sim partials ----------------
__global__ __launch_bounds__(256) void k_sim(const float* __restrict__ nrm,
                                             float* __restrict__ simP) {
  __shared__ float As[32 * 64];
  __shared__ float Bs[32 * 64];
  int bx = blockIdx.x;
  int ks = bx >> 6, tile = bx & 63;
  int bi = tile & 7, bj = tile >> 3;
  int t = threadIdx.x, tx = t & 15, ty = t >> 4;
  float acc[4][4] = {};
  int k0 = ks * (L_ / KS_);
  for (int kt = 0; kt < (L_ / KS_) / 32; ++kt) {
    for (int e = t; e < 2048; e += 256) {
      int kk = e >> 6, i = e & 63;
      int krow = k0 + kt * 32 + kk;
      As[e] = nrm[krow * N_ + bi * 64 + i];
      Bs[e] = nrm[krow * N_ + bj * 64 + i];
    }
    __syncthreads();
#pragma unroll
    for (int kk = 0; kk < 32; ++kk) {
      float4 a = *(const float4*)(As + kk * 64 + ty * 4);
      float4 b = *(const float4*)(Bs + kk * 64 + tx * 4);
      float av[4] = {a.x, a.y, a.z, a.w};
      float bv[4] = {b.x, b.y, b.z, b.w};
#pragma unroll
      for (int i = 0; i < 4; ++i)
#pragma unroll
        for (int j = 0; j < 4; ++j)
          acc[i][j] += av[i] * bv[j];
    }
    __syncthreads();
  }
  float* outp = simP + (size_t)ks * (N_ * N_);
#pragma unroll
  for (int i = 0; i < 4; ++i) {
    int row = bi * 64 + ty * 4 + i;
    float4 o = {acc[i][0], acc[i][1], acc[i][2], acc[i][3]};
    *(float4*)(outp + row * N_ + bj * 64 + tx * 4) = o;
  }
}

// ---------------- 3. simred (0-255) + psum collapse (256-287) ----------------
__global__ __launch_bounds__(256) void k_simred(const float* __restrict__ simP,
                                                float* __restrict__ sim,
                                                const float* __restrict__ psum,
                                                const float* __restrict__ psq,
                                                float* __restrict__ psumR,
                                                float* __restrict__ psqR) {
  int t = threadIdx.x;
  if (blockIdx.x < 256) {
    int gid = blockIdx.x * 256 + t;
    float4 s = {0.f, 0.f, 0.f, 0.f};
#pragma unroll
    for (int ksi = 0; ksi < KS_; ++ksi) {
      float4 p = *(const float4*)(simP + (size_t)ksi * (N_ * N_) + gid * 4);
      s.x += p.x; s.y += p.y; s.z += p.z; s.w += p.w;
    }
    *(float4*)(sim + gid * 4) = s;
    return;
  }
  int tid = (blockIdx.x - 256) * 256 + t;   // [0, 8192)
  const float* src = (tid < 4096) ? psum : psq;
  float* dst = (tid < 4096) ? psumR : psqR;
  int id = tid & 4095;
  int b = id >> 9, n = id & 511;
  float a = 0.f;
#pragma unroll 8
  for (int c = 0; c < 512; ++c)
    a += src[((size_t)b * 512 + c) * N_ + n];
  dst[id] = a;
}

// ---------------- 4. topk radix (0-127) + rfinal-lite (128-143) ----------------
__global__ __launch_bounds__(256) void k_tf(
    const float* __restrict__ sim, int* __restrict__ idx_t,
    const float* __restrict__ psumR, const float* __restrict__ psqR,
    const float* __restrict__ veq, const float* __restrict__ vek,
    const float* __restrict__ abc, const float* __restrict__ vei,
    float* __restrict__ Q, float* __restrict__ Kv,
    float* __restrict__ imp, float* __restrict__ summary) {
  int t = threadIdx.x;
  if (blockIdx.x < 128) {
    int lane = t & 63, wv = t >> 6;
    int n = blockIdx.x * 4 + wv;
    unsigned sv[8];
#pragma unroll
    for (int u = 0; u < 8; ++u) {
      int idx = u * 64 + lane;
      float f = (idx == n) ? -3e38f : sim[n * N_ + idx];
      unsigned xb = __float_as_uint(f);
      sv[u] = (xb & 0x80000000u) ? ~xb : (xb | 0x80000000u);
    }
    unsigned thr = 0u;
#pragma unroll
    for (int b = 31; b >= 0; --b) {
      unsigned cand = thr | (1u << b);
      int cnt = 0;
#pragma unroll
      for (int u = 0; u < 8; ++u)
        cnt += __popcll(__ballot(sv[u] >= cand));
      if (cnt >= TK_) thr = cand;
    }
    int cgt = 0;
#pragma unroll
    for (int u = 0; u < 8; ++u)
      cgt += __popcll(__ballot(sv[u] > thr));
    int need = TK_ - cgt;
    unsigned long long lt_mask = (lane == 0) ? 0ull : (~0ull >> (64 - lane));
    int written = 0, tie_seen = 0;
#pragma unroll
    for (int u = 0; u < 8; ++u) {
      bool gt = sv[u] > thr;
      bool eq = sv[u] == thr;
      unsigned long long me = __ballot(eq);
      bool sel = gt || (eq && (tie_seen + __popcll(me & lt_mask)) < need);
      unsigned long long ms = __ballot(sel);
      int pos = written + __popcll(ms & lt_mask);
      if (sel) idx_t[pos * N_ + n] = u * 64 + lane;
      written += __popcll(ms);
      tie_seen += __popcll(me);
    }
    return;
  }
  int gid = (blockIdx.x - 128) * 256 + t;
  int b = gid >> 9, n = gid & 511;
  float s  = psumR[gid];
  float ss = psqR[gid];
  float mean = s * (1.f / L_);
  float var  = fmaxf((ss - s * mean) * (1.f / (L_ - 1)), 0.f);
  float stdv = sqrtf(var + 1e-5f);
  summary[b * N_ + n] = mean;
#pragma unroll
  for (int h = 0; h < 16; ++h) {
    Q[(b * N_ + n) * 16 + h]  = veq[n * 16 + h] + mean * abc[h]      + stdv * abc[16 + h] + abc[32 + h];
    Kv[(b * N_ + n) * 16 + h] = vek[n * 16 + h] + mean * abc[48 + h] + stdv * abc[64 + h] + abc[80 + h];
  }
  imp[b * N_ + n] = sigmoidf_(vei[n] + mean * abc[96] + stdv * abc[97] + abc[98]);
}

// ---------------- 5. weight prep + ct partials ----------------
__global__ __launch_bounds__(256) void k_wprep(const float* __restrict__ gate_w,
                                               const float* __restrict__ fus_w,
                                               const float* __restrict__ cw,
                                               const float* __restrict__ misc,
                                               const float* __restrict__ summ,
                                               const float* __restrict__ cg_w,
                                               const float* __restrict__ cg_b,
                                               short* __restrict__ wt_gate,
                                               short* __restrict__ wt_fus,
                                               short* __restrict__ w2t,
                                               short* __restrict__ cwb,
                                               float* __restrict__ ctP) {
  __shared__ float tile[32][33];
  __shared__ float ssum[8][64];
  int blk = blockIdx.x, t = threadIdx.x;
  if (blk < 512) {
    const float* W = (blk < 256) ? gate_w : fus_w;
    short* Wt = (blk < 256) ? wt_gate : wt_fus;
    int ldd = (blk < 256) ? 1024 : 512;
    int b2 = blk & 255;
    int bk = b2 >> 4, bn = b2 & 15;
    int c = t & 31, r = t >> 5;
    for (int rr = r; rr < 32; rr += 8)
      tile[rr][c] = W[(size_t)(bk * 32 + rr) * 512 + bn * 32 + c];
    __syncthreads();
    for (int rr = r; rr < 32; rr += 8)
      Wt[(size_t)(bn * 32 + rr) * ldd + bk * 32 + c] = f2bf(tile[c][rr]);
  } else if (blk < 544) {
    int gid = (blk - 512) * 256 + t;
    int c = gid >> 9, n = gid & 511;
    float a = 0.f;
    for (int m = 0; m < 512; ++m)
      a += cw[m * 16 + c] * gate_w[(size_t)(512 + m) * 512 + n];
    wt_gate[(size_t)n * 1024 + 512 + c] = f2bf(a);
    wt_gate[(size_t)n * 1024 + 528 + c] = 0;
    wt_gate[(size_t)n * 1024 + 544 + c] = 0;
    wt_gate[(size_t)n * 1024 + 560 + c] = 0;
  } else if (blk < 672) {
    int gid = (blk - 544) * 256 + t;
    int d = gid >> 9, m = gid & 511;
    float a = 0.f;
#pragma unroll
    for (int c = 0; c < 16; ++c)
      a += cw[m * 16 + c] * misc[96 + c * 64 + d];
    w2t[d * 512 + m] = f2bf(a);
  } else if (blk < 736) {
    int gid = (blk - 672) * 256 + t;
    int n = gid >> 5, kk = gid & 31;
    cwb[gid] = (kk < 16) ? f2bf(cw[n * 16 + kk]) : (short)0;
  } else {
    int bx = blk - 736;
    int oc = bx & 31;
    int nc = bx >> 5;
    int n0 = nc * 64;
    for (int e = t; e < 512; e += 256)
      ssum[e >> 6][e & 63] = summ[(e >> 6) * 512 + n0 + (e & 63)];
    __syncthreads();
    int b = t >> 5, ol = t & 31;
    int o = oc * 32 + ol;
    float acc = (nc == 0) ? cg_b[o] : 0.f;
#pragma unroll 8
    for (int k = 0; k < 64; ++k)
      acc += ssum[b][k] * cg_w[(size_t)(n0 + k) * 1024 + o];
    ctP[(nc * 8 + b) * 1024 + o] = acc;
  }
}

// ---------------- 6. ctp (0-31) + attn (32-1055) + xcp (1056-1311) ----------------
__global__ __launch_bounds__(256) void k_caxc(const float* __restrict__ ctP,
                                              const float* __restrict__ cp1_w,
                                              const float* __restrict__ cp1_b,
                                              const float* __restrict__ misc,
                                              float* __restrict__ ctp,
                                              const float* __restrict__ Q,
                                              const float* __restrict__ Kv,
                                              const int* __restrict__ idx_t,
                                              short* __restrict__ At,
                                              const short* __restrict__ xbf,
                                              const short* __restrict__ w2t,
                                              float* __restrict__ xcp) {
  __shared__ float cts[256];
  __shared__ short rowbuf[4][512];
  __shared__ __align__(16) short As[2][64 * 32];
  __shared__ __align__(16) short Bs[2][64 * 32];
  int blk = blockIdx.x, t = threadIdx.x;
  if (blk < 32) {
    int row0 = blk * 4;
    int b = row0 >> 4, c0 = row0 & 15;
    {
      int idx = (c0 + (t >> 6)) * 64 + (t & 63);
      float a = 0.f;
#pragma unroll
      for (int p = 0; p < 8; ++p) a += ctP[(p * 8 + b) * 1024 + idx];
      cts[t] = a;
    }
    __syncthreads();
    int lr = t >> 6, d2 = t & 63;
    float a = cp1_b[d2] + misc[80 + d2];
#pragma unroll 8
    for (int d = 0; d < 64; ++d) a += cts[lr * 64 + d] * cp1_w[d * 64 + d2];
    ctp[(row0 + lr) * 64 + d2] = a;
  } else if (blk < 32 + 1024) {
    int w = t >> 6, j = t & 63;
    int bn = (blk - 32) * 4 + w;
    int b = bn >> 9, n = bn & (N_ - 1);
    ((int4*)rowbuf[w])[j] = int4{0, 0, 0, 0};
    float s = -3e38f;
    int m = 0;
    if (j < TK_) {
      m = idx_t[j * N_ + n];
      const float* qp = Q + (b * N_ + n) * H_;
      const float* kp = Kv + (b * N_ + m) * H_;
      float a = 0.f;
#pragma unroll
      for (int h = 0; h < H_; ++h) a += qp[h] * kp[h];
      s = a * 0.25f;
    }
    float mx = s;
#pragma unroll
    for (int o = 32; o > 0; o >>= 1) mx = fmaxf(mx, __shfl_xor(mx, o));
    float e = (j < TK_) ? expf(s - mx) : 0.f;
    float sum = e;
#pragma unroll
    for (int o = 32; o > 0; o >>= 1) sum += __shfl_xor(sum, o);
    __syncthreads();
    if (j < TK_) rowbuf[w][m] = f2bf(e / sum);
    __syncthreads();
    ((int4*)(At + (size_t)bn * 512))[j] = ((int4*)rowbuf[w])[j];
  } else {
    int lane = t & 63, w = t >> 6;
    int lo = lane & 15, hi = lane >> 4;
    int row0 = (blk - 1056) * 64;
    f32x4 acc[4] = {};
    int rA = t >> 2, cA = (t & 3) ^ ((rA >> 1) & 3);
    const short* srcA = xbf + (size_t)(row0 + rA) * 512 + cA * 8;
    const short* srcB = w2t + (size_t)rA * 512 + cA * 8;
    int gl = (lo >> 1) & 3;
    int foff = (lo * 4 + (hi ^ gl)) * 8;
    gload16(srcA, As[0] + t * 8);
    gload16(srcB, Bs[0] + t * 8);
    __syncthreads();
    int cur = 0;
    for (int kt = 0; kt < 16; ++kt) {
      if (kt < 15) {
        gload16(srcA + (kt + 1) * 32, As[cur ^ 1] + t * 8);
        gload16(srcB + (kt + 1) * 32, Bs[cur ^ 1] + t * 8);
      }
      bf16x8 b = *(const bf16x8*)(Bs[cur] + (w * 64) * 8 + foff);
#pragma unroll
      for (int m = 0; m < 4; ++m) {
        bf16x8 a = *(const bf16x8*)(As[cur] + (m * 64) * 8 + foff);
        acc[m] = __builtin_amdgcn_mfma_f32_16x16x32_bf16(a, b, acc[m], 0, 0, 0);
      }
      __syncthreads();
      cur ^= 1;
    }
#pragma unroll
    for (int m = 0; m < 4; ++m)
#pragma unroll
      for (int j = 0; j < 4; ++j) {
        int row = row0 + m * 16 + hi * 4 + j;
        int col = w * 16 + lo;
        xcp[(size_t)row * 64 + col] = acc[m][j];
      }
  }
}

// ---------------- 7. rgemm triple-buffered counted-vmcnt (0-511) + s2 (512-1023) ----------------
__global__ __launch_bounds__(512) void k_sg(const short* __restrict__ xbf,
                                            const short* __restrict__ At,
                                            const float* __restrict__ imp,
                                            short* __restrict__ abuf,
                                            const float* __restrict__ xcp,
                                            const float* __restrict__ ctp,
                                            const float* __restrict__ misc) {
  __shared__ __align__(16) short As[3][128 * 32];
  __shared__ __align__(16) short Bs[3][128 * 32];
  int blk = blockIdx.x, t = threadIdx.x;
  int lane = t & 63, w = t >> 6;
  if (blk < 512) {
    int vid = ((blk & 7) << 6) | (blk >> 3);   // bijective XCD swizzle
    int lo = lane & 15, hi = lane >> 4;
    int b = vid >> 6;
    int tile = vid & 63;
    int bm = tile >> 2, bn = tile & 3;
    int row0 = b * L_ + bm * 128, n0 = bn * 128;
    int wm = w >> 2, wn = w & 3;
    f32x4 acc[4][2] = {};
    int rs = t >> 2, cs = (t & 3) ^ ((rs >> 1) & 3);
    const short* sA = xbf + (size_t)(row0 + rs) * 512 + cs * 8;
    const short* sB = At + ((size_t)b * N_ + n0 + rs) * 512 + cs * 8;
    int gl = (lo >> 1) & 3;
    int foff = (lo * 4 + (hi ^ gl)) * 8;
    // prologue: tiles 0,1,2 in flight (2 loads each per wave)
    gload16(sA,      As[0] + t * 8);  gload16(sB,      Bs[0] + t * 8);
    gload16(sA + 32, As[1] + t * 8);  gload16(sB + 32, Bs[1] + t * 8);
    gload16(sA + 64, As[2] + t * 8);  gload16(sB + 64, Bs[2] + t * 8);
    for (int i = 0; i < 16; ++i) {
      if (i <= 13)      { WAITV(4); }   // tiles i+1,i+2 may stay in flight
      else if (i == 14) { WAITV(2); }
      else              { WAITV(0); }
      SBAR();
      int cur = i % 3;
      bf16x8 a[4], bb[2];
#pragma unroll
      for (int m = 0; m < 4; ++m)
        a[m] = *(const bf16x8*)(As[cur] + (wm * 64 + m * 16) * 32 + foff);
#pragma unroll
      for (int n = 0; n < 2; ++n)
        bb[n] = *(const bf16x8*)(Bs[cur] + (wn * 32 + n * 16) * 32 + foff);
#pragma unroll
      for (int m = 0; m < 4; ++m)
#pragma unroll
        for (int n = 0; n < 2; ++n)
          acc[m][n] = __builtin_amdgcn_mfma_f32_16x16x32_bf16(a[m], bb[n], acc[m][n], 0, 0, 0);
      SBAR();
      if (i <= 12) {
        gload16(sA + (i + 3) * 32, As[cur] + t * 8);
        gload16(sB + (i + 3) * 32, Bs[cur] + t * 8);
      }
    }
#pragma unroll
    for (int m = 0; m < 4; ++m) {
      int rbase = row0 + wm * 64 + m * 16 + hi * 4;
#pragma unroll
      for (int j = 0; j < 4; ++j) {
        int row = rbase + j;
#pragma unroll
        for (int n = 0; n < 2; ++n) {
          int col = n0 + wn * 32 + n * 16 + lo;
          float iv = imp[b * N_ + col];
          float xv = bf2f(xbf[(size_t)row * 512 + col]);
          abuf[(size_t)row * 1024 + col] = f2bf(iv * acc[m][n][j] + (1.f - iv) * xv);
        }
      }
    }
  } else {
    // s2: thread-per-(row,c), LDS-staged, no cross-lane ops
    float* xcps = (float*)As;               // 32 x 65 floats
    float* ctps = (float*)Bs;               // 16 x 65 floats
    float* cp2sd = ((float*)Bs) + 1100;     // 65 floats
    int row0 = (blk - 512) * 32;
    int b = row0 >> 11;
    for (int e = t; e < 32 * 64; e += 512)
      xcps[(e >> 6) * 65 + (e & 63)] = xcp[(size_t)(row0 + (e >> 6)) * 64 + (e & 63)];
    for (int e = t; e < 16 * 64; e += 512)
      ctps[(e >> 6) * 65 + (e & 63)] = ctp[b * 1024 + e];
    if (t < 65) cp2sd[t] = misc[t];
    __syncthreads();
    int r = t >> 4, c = t & 15;
    const float* xr = xcps + r * 65;
    const float* cc = ctps + c * 65;
    float acc = 0.f;
#pragma unroll 8
    for (int d = 0; d < 64; ++d) {
      float u = cc[d] + xr[d];
      float g = 0.5f * u * (1.f + erff(u * 0.70710678118654752f));
      acc += g * cp2sd[d];
    }
    int row = row0 + r;
    abuf[(size_t)row * 1024 + 512 + c] = f2bf(acc + cp2sd[64]);
    abuf[(size_t)row * 1024 + 528 + c] = 0;
    abuf[(size_t)row * 1024 + 544 + c] = 0;
    abuf[(size_t)row * 1024 + 560 + c] = 0;
  }
}

// ---------------- 8. gate GEMM triple-buffered counted-vmcnt (K=544, 17 BK-32 tiles) ----------------
__global__ __launch_bounds__(512) void k_gemm_gate(const short* __restrict__ abuf,
                                                   const short* __restrict__ wt,
                                                   const short* __restrict__ cwb,
                                                   const float* __restrict__ gate_b,
                                                   short* __restrict__ fused_bf) {
  __shared__ __align__(16) short As[3][128 * 32];
  __shared__ __align__(16) short Bs[3][128 * 32];
  int t = threadIdx.x, lane = t & 63, w = t >> 6;
  int lo = lane & 15, hi = lane >> 4;
  int vid = ((blockIdx.x & 7) << 6) | (blockIdx.x >> 3);
  int bm = vid >> 2, bn = vid & 3;
  int row0 = bm * 128, n0 = bn * 128;
  int wm = w >> 2, wn = w & 3;
  f32x4 acc[4][2] = {};
  f32x4 acc2[4][2] = {};
  int rs = t >> 2, cs = (t & 3) ^ ((rs >> 1) & 3);
  int gl = (lo >> 1) & 3;
  int foff = (lo * 4 + (hi ^ gl)) * 8;
  // ---- acc2 prologue (plain __syncthreads, clean drain) ----
  gload16(abuf + (size_t)(row0 + rs) * 1024 + 512 + cs * 8, As[0] + t * 8);
  gload16(cwb + (size_t)(n0 + rs) * 32 + cs * 8, Bs[0] + t * 8);
  __syncthreads();
  {
    bf16x8 a[4], bb[2];
#pragma unroll
    for (int m = 0; m < 4; ++m)
      a[m] = *(const bf16x8*)(As[0] + (wm * 64 + m * 16) * 32 + foff);
#pragma unroll
    for (int n = 0; n < 2; ++n)
      bb[n] = *(const bf16x8*)(Bs[0] + (wn * 32 + n * 16) * 32 + foff);
#pragma unroll
    for (int m = 0; m < 4; ++m)
#pragma unroll
      for (int n = 0; n < 2; ++n)
        acc2[m][n] = __builtin_amdgcn_mfma_f32_16x16x32_bf16(a[m], bb[n], acc2[m][n], 0, 0, 0);
  }
  __syncthreads();
  // ---- main pipeline: 17 tiles, 3 in flight ----
  const short* sA = abuf + (size_t)(row0 + rs) * 1024 + cs * 8;
  const short* sB = wt + (size_t)(n0 + rs) * 1024 + cs * 8;
  gload16(sA,      As[0] + t * 8);  gload16(sB,      Bs[0] + t * 8);
  gload16(sA + 32, As[1] + t * 8);  gload16(sB + 32, Bs[1] + t * 8);
  gload16(sA + 64, As[2] + t * 8);  gload16(sB + 64, Bs[2] + t * 8);
  for (int i = 0; i < 17; ++i) {
    if (i <= 14)      { WAITV(4); }
    else if (i == 15) { WAITV(2); }
    else              { WAITV(0); }
    SBAR();
    int cur = i % 3;
    bf16x8 a[4], bb[2];
#pragma unroll
    for (int m = 0; m < 4; ++m)
      a[m] = *(const bf16x8*)(As[cur] + (wm * 64 + m * 16) * 32 + foff);
#pragma unroll
    for (int n = 0; n < 2; ++n)
      bb[n] = *(const bf16x8*)(Bs[cur] + (wn * 32 + n * 16) * 32 + foff);
#pragma unroll
    for (int m = 0; m < 4; ++m)
#pragma unroll
      for (int n = 0; n < 2; ++n)
        acc[m][n] = __builtin_amdgcn_mfma_f32_16x16x32_bf16(a[m], bb[n], acc[m][n], 0, 0, 0);
    SBAR();
    if (i <= 13) {
      gload16(sA + (i + 3) * 32, As[cur] + t * 8);
      gload16(sB + (i + 3) * 32, Bs[cur] + t * 8);
    }
  }
#pragma unroll
  for (int m = 0; m < 4; ++m) {
    int rbase = row0 + wm * 64 + m * 16 + hi * 4;
#pragma unroll
    for (int j = 0; j < 4; ++j) {
      int row = rbase + j;
#pragma unroll
      for (int n = 0; n < 2; ++n) {
        int col = n0 + wn * 32 + n * 16 + lo;
        float g = sigmoidf_(acc[m][n][j] + gate_b[col]);
        float ringv = bf2f(abuf[(size_t)row * 1024 + col]);
        fused_bf[(size_t)row * 512 + col] = f2bf(g * ringv + (1.f - g) * acc2[m][n][j]);
      }
    }
  }
}

// ---------------- 9. fus GEMM (XCD-swizzled, pipelined) + residual + LayerNorm ----------------
__global__ __launch_bounds__(512) void k_gemm_fus(const short* __restrict__ fused_bf,
                                                  const short* __restrict__ wtf,
                                                  const float* __restrict__ x,
                                                  const float* __restrict__ fus_b,
                                                  const float* __restrict__ ln_g,
                                                  const float* __restrict__ ln_b,
                                                  float* __restrict__ out) {
  __shared__ __align__(16) short As[2][64 * 32];
  __shared__ __align__(16) short Bs[2][512 * 32];
  __shared__ float Ssh[8][64], Qsh[8][64];
  __shared__ float mus[64], rss[64];
  int t = threadIdx.x, lane = t & 63, w = t >> 6;
  int lo = lane & 15, hi = lane >> 4;
  int vid = ((blockIdx.x & 7) << 5) | (blockIdx.x >> 3);
  int row0 = vid * 64;
  f32x4 acc[4][4] = {};
  int pA = w * 64 + lane;
  int rA = pA >> 2, cA = (pA & 3) ^ ((rA >> 1) & 3);
  const short* srcA = fused_bf + (size_t)(row0 + rA) * 512 + cA * 8;
  int rB[4], cB[4];
  const short* srcB[4];
#pragma unroll
  for (int q = 0; q < 4; ++q) {
    int pB = w * 256 + q * 64 + lane;
    rB[q] = pB >> 2; cB[q] = (pB & 3) ^ ((rB[q] >> 1) & 3);
    srcB[q] = wtf + (size_t)rB[q] * 512 + cB[q] * 8;
  }
  int gl = (lo >> 1) & 3;
  int foff = (lo * 4 + (hi ^ gl)) * 8;
  if (w < 4) gload16(srcA, As[0] + pA * 8);
#pragma unroll
  for (int q = 0; q < 4; ++q)
    gload16(srcB[q], Bs[0] + (w * 256 + q * 64) * 8);
  __syncthreads();
  int cur = 0;
  for (int i = 0; i < 16; ++i) {
    if (i < 15) {
      int kt = i + 1;
      if (w < 4) gload16(srcA + kt * 32, As[cur ^ 1] + pA * 8);
#pragma unroll
      for (int q = 0; q < 4; ++q)
        gload16(srcB[q] + kt * 32, Bs[cur ^ 1] + (w * 256 + q * 64) * 8);
    }
    bf16x8 a[4], b[4];
#pragma unroll
    for (int m = 0; m < 4; ++m)
      a[m] = *(const bf16x8*)(As[cur] + (m * 64) * 8 + foff);
#pragma unroll
    for (int n = 0; n < 4; ++n)
      b[n] = *(const bf16x8*)(Bs[cur] + (w * 256 + n * 64) * 8 + foff);
#pragma unroll
    for (int m = 0; m < 4; ++m)
#pragma unroll
      for (int n = 0; n < 4; ++n)
        acc[m][n] = __builtin_amdgcn_mfma_f32_16x16x32_bf16(a[m], b[n], acc[m][n], 0, 0, 0);
    __syncthreads();
    cur ^= 1;
  }
#pragma unroll
  for (int m = 0; m < 4; ++m) {
#pragma unroll
    for (int j = 0; j < 4; ++j) {
      int rl = m * 16 + hi * 4 + j;
      int row = row0 + rl;
      float ps = 0.f, pq = 0.f;
#pragma unroll
      for (int n = 0; n < 4; ++n) {
        int col = w * 64 + n * 16 + lo;
        float h = acc[m][n][j] + fus_b[col] + x[(size_t)row * 512 + col];
        acc[m][n][j] = h;
        ps += h; pq += h * h;
      }
#pragma unroll
      for (int o = 1; o < 16; o <<= 1) {
        ps += __shfl_xor(ps, o);
        pq += __shfl_xor(pq, o);
      }
      if (lo == 0) { Ssh[w][rl] = ps; Qsh[w][rl] = pq; }
    }
  }
  __syncthreads();
  if (t < 64) {
    float s = 0.f, q = 0.f;
#pragma unroll
    for (int ww = 0; ww < 8; ++ww) { s += Ssh[ww][t]; q += Qsh[ww][t]; }
    float mu = s * (1.f / N_);
    float var = q * (1.f / N_) - mu * mu;
    mus[t] = mu;
    rss[t] = rsqrtf(fmaxf(var, 0.f) + 1e-5f);
  }
  __syncthreads();
#pragma unroll
  for (int m = 0; m < 4; ++m) {
#pragma unroll
    for (int j = 0; j < 4; ++j) {
      int rl = m * 16 + hi * 4 + j;
      int row = row0 + rl;
      float mu = mus[rl], rs = rss[rl];
#pragma unroll
      for (int n = 0; n < 4; ++n) {
        int col = w * 64 + n * 16 + lo;
        out[(size_t)row * 512 + col] = (acc[m][n][j] - mu) * rs * ln_g[col] + ln_b[col];
      }
    }
  }
}

extern "C" void kernel_launch(void* const* d_in, const int* in_sizes, int n_in,
                              void* d_out, int out_size, void* d_ws, size_t ws_size,
                              hipStream_t stream) {
  (void)in_sizes; (void)n_in; (void)out_size; (void)ws_size;
  const float* x         = (const float*)d_in[0];
  const float* var_embed = (const float*)d_in[1];
  const float* temp_w    = (const float*)d_in[2];
  const float* temp_b    = (const float*)d_in[3];
  const float* q_w       = (const float*)d_in[4];
  const float* q_b       = (const float*)d_in[5];
  const float* k_w       = (const float*)d_in[6];
  const float* k_b       = (const float*)d_in[7];
  const float* imp_w     = (const float*)d_in[8];
  const float* imp_b     = (const float*)d_in[9];
  const float* cluster   = (const float*)d_in[10];
  const float* vp_w      = (const float*)d_in[11];
  const float* vp_b      = (const float*)d_in[12];
  const float* cp1_w     = (const float*)d_in[13];
  const float* cp1_b     = (const float*)d_in[14];
  const float* cp2_w     = (const float*)d_in[15];
  const float* cp2_b     = (const float*)d_in[16];
  const float* cg_w      = (const float*)d_in[17];
  const float* cg_b      = (const float*)d_in[18];
  const float* gate_w    = (const float*)d_in[19];
  const float* gate_b    = (const float*)d_in[20];
  const float* fus_w     = (const float*)d_in[21];
  const float* fus_b     = (const float*)d_in[22];
  const float* ln_g      = (const float*)d_in[23];
  const float* ln_b      = (const float*)d_in[24];
  float* out = (float*)d_out;
  float* ws  = (float*)d_ws;

  float* normed = ws + 0;                 // 4 MB (xcp reuses)
  int*   idx_t  = (int*)(ws + 1310720);
  float* Qb     = ws + 1335296;
  float* Kb     = ws + 1400832;
  float* impb   = ws + 1466368;
  float* summ   = ws + 1470464;
  float* cw     = ws + 1658880;
  float* ctp    = ws + 1675264;
  float* misc   = ws + 1683456;
  short* w2t    = (short*)(ws + 1693696);
  short* cwb    = (short*)(ws + 1710080);
  short* abuf     = (short*)(ws + 1720320);   // 32 MB
  short* fused_bf = (short*)(ws + 10108928);  // 16 MB (also xbf)
  short* wt_gate  = (short*)(ws + 14303232);
  short* wt_fus   = (short*)(ws + 14565376);
  float* ctP      = ws + 15220736;
  short* At       = (short*)(ws + 15286272);  // 4 MB
  float* sim      = ws + 16334848;
  float* veq      = ws + 16596992;
  float* vek      = ws + 16605184;
  float* abc      = ws + 16613376;
  float* vei      = ws + 16613504;
  float* psum     = ws + 17000000;            // 8*512*512
  float* psq      = ws + 19200000;
  float* psumR    = ws + 21400000;
  float* psqR     = ws + 21410000;
  float* simP = (float*)abuf;   // dead after k_simred
  float* xcp  = normed;
  short* xbf  = fused_bf;

  k_pre<<<548, 512, 0, stream>>>(x, var_embed, temp_w, temp_b, q_w, q_b, k_w, k_b,
                                 imp_w, imp_b, cluster, cp2_w, cp2_b, vp_b, vp_w,
                                 cp1_w, normed, psum, psq, xbf, veq, vek, abc, vei,
                                 cw, misc);
  k_sim<<<64 * KS_, 256, 0, stream>>>(normed, simP);
  k_simred<<<288, 256, 0, stream>>>(simP, sim, psum, psq, psumR, psqR);
  k_tf<<<144, 256, 0, stream>>>(sim, idx_t, psumR, psqR, veq, vek, abc, vei,
                                Qb, Kb, impb, summ);
  k_wprep<<<992, 256, 0, stream>>>(gate_w, fus_w, cw, misc, summ, cg_w, cg_b,
                                   wt_gate, wt_fus, w2t, cwb, ctP);
  k_caxc<<<1312, 256, 0, stream>>>(ctP, cp1_w, cp1_b, misc, ctp, Qb, Kb, idx_t,
                                   At, xbf, w2t, xcp);
  k_sg<<<1024, 512, 0, stream>>>(xbf, At, impb, abuf, xcp, ctp, misc);
  k_gemm_gate<<<512, 512, 0, stream>>>(abuf, wt_gate, cwb, gate_b, fused_bf);
  k_gemm_fus<<<256, 512, 0, stream>>>(fused_bf, wt_fus, x, fus_b, ln_g, ln_b, out);
}